// Round 10
// baseline (344.265 us; speedup 1.0000x reference)
//
#include <hip/hip_runtime.h>

typedef unsigned short u16;
typedef unsigned int u32;
typedef __attribute__((ext_vector_type(8))) short bf16x8;
typedef __attribute__((ext_vector_type(4))) float f32x4;

#define HID 2048
#define S_LEN 1024
#define BATCH 2
#define G_KV 8
#define R_REP 4
#define HD 64
#define NQKV 3072  // 2048 q + 512 k + 512 v

__device__ __forceinline__ u16 f2bf(float f) {
    union { u32 u; float ff; } x; x.ff = f;
    u32 u = x.u;
    u += 0x7FFFu + ((u >> 16) & 1u);
    return (u16)(u >> 16);
}

__device__ __forceinline__ void gload_lds16(const void* g, void* l) {
    __builtin_amdgcn_global_load_lds((const __attribute__((address_space(1))) void*)g,
                                     (__attribute__((address_space(3))) void*)l,
                                     16, 0, 0);
}

// ------- Fused prep: cvt_x | transpose_qkv | transpose_cvt(Wo) (R8-proven) -------
__global__ __launch_bounds__(256) void prep(const float* __restrict__ x,
                                            const float* __restrict__ Wq,
                                            const float* __restrict__ Wk,
                                            const float* __restrict__ Wv,
                                            const float* __restrict__ Wo,
                                            u16* __restrict__ Xb,
                                            u16* __restrict__ WqkvT,
                                            u16* __restrict__ WoT) {
    __shared__ float tile[32][33];
    int bid = blockIdx.x, tid = threadIdx.x;

    if (bid < 2048) {
        int i = (bid * 256 + tid) * 8;
        float4 a = *(const float4*)(x + i);
        float4 b = *(const float4*)(x + i + 4);
        u16 t[8] = {f2bf(a.x), f2bf(a.y), f2bf(a.z), f2bf(a.w),
                    f2bf(b.x), f2bf(b.y), f2bf(b.z), f2bf(b.w)};
        *(uint4*)(Xb + i) = *(const uint4*)t;
        return;
    }

    int tx = tid & 31, ty = tid >> 5;
    if (bid < 8192) {
        int local = bid - 2048;
        int n0 = (local % 96) * 32, k0 = (local / 96) * 32;
        const float* in; int N, nc0;
        if (n0 < 2048)      { in = Wq; N = 2048; nc0 = n0; }
        else if (n0 < 2560) { in = Wk; N = 512;  nc0 = n0 - 2048; }
        else                { in = Wv; N = 512;  nc0 = n0 - 2560; }
#pragma unroll
        for (int j = 0; j < 4; ++j)
            tile[ty + j * 8][tx] = in[(size_t)(k0 + ty + j * 8) * N + nc0 + tx];
        __syncthreads();
#pragma unroll
        for (int j = 0; j < 4; ++j)
            WqkvT[(size_t)(n0 + ty + j * 8) * 2048 + k0 + tx] = f2bf(tile[tx][ty + j * 8]);
        return;
    }

    {
        int local = bid - 8192;
        int n0 = (local & 63) * 32, k0 = (local >> 6) * 32;
#pragma unroll
        for (int j = 0; j < 4; ++j)
            tile[ty + j * 8][tx] = Wo[(size_t)(k0 + ty + j * 8) * 2048 + n0 + tx];
        __syncthreads();
#pragma unroll
        for (int j = 0; j < 4; ++j)
            WoT[(size_t)(n0 + ty + j * 8) * 2048 + k0 + tx] = f2bf(tile[tx][ty + j * 8]);
    }
}

// ------- QKV GEMM: BM=64 BN=128 BK=32, 768 blocks (3/CU); R1/R8-exact (best) -------
__global__ __launch_bounds__(256) void gemm_qkv(const u16* __restrict__ Xb,
                                                const u16* __restrict__ WT,
                                                const float* __restrict__ bq,
                                                const float* __restrict__ bk,
                                                const float* __restrict__ bv,
                                                u16* __restrict__ qb,
                                                u16* __restrict__ kb,
                                                u16* __restrict__ vb) {
    __shared__ __align__(16) u16 As[2][64 * 32];
    __shared__ __align__(16) u16 Bs[2][128 * 32];
    int tid = threadIdx.x;
    int w = tid >> 6, lane = tid & 63, quad = lane >> 4, l16 = lane & 15;
    int m0 = blockIdx.y * 64, n0 = blockIdx.x * 128;
    int wr = (w >> 1) * 32, wc = (w & 1) * 64;   // wave tile 32x64
    int srow = lane >> 2, scol = (lane & 3) * 8;

    const u16* aP  = &Xb[(size_t)(m0 + w * 16 + srow) * 2048 + scol];
    const u16* bP0 = &WT[(size_t)(n0 + w * 32 + srow) * 2048 + scol];
    const u16* bP1 = &WT[(size_t)(n0 + w * 32 + 16 + srow) * 2048 + scol];

    f32x4 acc[2][4];
#pragma unroll
    for (int i = 0; i < 2; ++i)
#pragma unroll
        for (int j = 0; j < 4; ++j) acc[i][j] = (f32x4){0.f, 0.f, 0.f, 0.f};

    gload_lds16(aP,  &As[0][(w * 16) * 32]);
    gload_lds16(bP0, &Bs[0][(w * 32) * 32]);
    gload_lds16(bP1, &Bs[0][(w * 32 + 16) * 32]);
    __syncthreads();

    int cur = 0;
    for (int k0 = 0; k0 < 2048; k0 += 32) {
        int kn = k0 + 32;
        if (kn < 2048) {
            gload_lds16(aP + kn,  &As[cur ^ 1][(w * 16) * 32]);
            gload_lds16(bP0 + kn, &Bs[cur ^ 1][(w * 32) * 32]);
            gload_lds16(bP1 + kn, &Bs[cur ^ 1][(w * 32 + 16) * 32]);
        }
        bf16x8 af[2], bfr[4];
#pragma unroll
        for (int mt = 0; mt < 2; ++mt)
            af[mt] = *(const bf16x8*)&As[cur][(wr + mt * 16 + l16) * 32 + quad * 8];
#pragma unroll
        for (int nt = 0; nt < 4; ++nt)
            bfr[nt] = *(const bf16x8*)&Bs[cur][(wc + nt * 16 + l16) * 32 + quad * 8];
#pragma unroll
        for (int mt = 0; mt < 2; ++mt)
#pragma unroll
            for (int nt = 0; nt < 4; ++nt)
                acc[mt][nt] = __builtin_amdgcn_mfma_f32_16x16x32_bf16(af[mt], bfr[nt], acc[mt][nt], 0, 0, 0);
        __syncthreads();
        cur ^= 1;
    }

#pragma unroll
    for (int nt = 0; nt < 4; ++nt) {
        int n = n0 + wc + nt * 16 + l16;
        float bias;
        if (n < 2048) bias = bq[n];
        else if (n < 2560) bias = bk[n - 2048];
        else bias = bv[n - 2560];
#pragma unroll
        for (int mt = 0; mt < 2; ++mt) {
#pragma unroll
            for (int reg = 0; reg < 4; ++reg) {
                int m = m0 + wr + mt * 16 + quad * 4 + reg;
                float val = acc[mt][nt][reg] + bias;
                int b = m >> 10, s = m & 1023;
                if (n < 2048) {
                    int g = n >> 8, r = (n >> 6) & 3, d = n & 63;
                    qb[((((size_t)(b * G_KV + g) * R_REP + r) * S_LEN) + s) * HD + d] = f2bf(val * 0.125f);
                } else if (n < 2560) {
                    int n2 = n - 2048, g = n2 >> 6, d = n2 & 63;
                    kb[(((size_t)(b * G_KV + g) * S_LEN) + s) * HD + d] = f2bf(val);
                } else {
                    int n2 = n - 2560, g = n2 >> 6, d = n2 & 63;
                    vb[(((size_t)(b * G_KV + g) * HD + d) * S_LEN) + s] = f2bf(val);  // V^T
                }
            }
        }
    }
}

// ------- Attention v3: no K/V/mask LDS staging, barrier-free main loop.
//         K/V per (b,g) = 256KB (L2-resident, 64 blocks share); within a block the
//         4 waves' fragment reads are L1-hits. Staging bought no traffic reduction
//         (each byte read once per block either way) and cost 32KB LDS writes +
//         2 barriers per kt. Direct 16B-aligned coalesced global reads instead.
//         LDS: only wave-private Ps strips + l_lds (9.5 KB). -------
__global__ __launch_bounds__(256) void attn_mfma(const u16* __restrict__ qbuf,
                                                 const u16* __restrict__ kbuf,
                                                 const u16* __restrict__ vtbuf,
                                                 const float* __restrict__ mask,
                                                 u16* __restrict__ aout) {
    __shared__ __align__(16) u16 Ps[64 * 72];   // [wave-strip q][key] bf16
    __shared__ float l_lds[64];

    int d = blockIdx.x;                   // 1024 = B*G*64
    int qblk = d & 63, g = (d >> 6) & 7, b = d >> 9;
    int s0 = qblk * 16;

    int tid = threadIdx.x;
    int w = tid >> 6, lane = tid & 63, quad = lane >> 4, l16 = lane & 15;
    int qs = w * 16 + l16;                // wave-private strip row

    // Q: head r = w, rows s0..s0+15; lane's q-col = l16 (pre-scaled by 1/8 in gemm_qkv)
    const u16* qrow = qbuf +
        ((((size_t)(b * G_KV + g) * R_REP + w) * S_LEN) + s0 + l16) * HD;
    bf16x8 qf0 = *(const bf16x8*)(qrow + quad * 8);
    bf16x8 qf1 = *(const bf16x8*)(qrow + 32 + quad * 8);

    f32x4 o_acc[4];
#pragma unroll
    for (int i = 0; i < 4; ++i) o_acc[i] = (f32x4){0.f, 0.f, 0.f, 0.f};
    float l_part = 0.f;

    const u16* kbase  = kbuf  + (size_t)(b * G_KV + g) * S_LEN * HD;
    const u16* vtbase = vtbuf + (size_t)(b * G_KV + g) * HD * S_LEN;
    // per-lane mask base: row (s0+l16), cols quad*4 + kt*64 + mt*16
    const float* mrow = mask + ((size_t)b * S_LEN + s0 + l16) * S_LEN + quad * 4;

    for (int kt = 0; kt < 16; ++kt) {
        int kk = kt * 64;

        // S^T = K * Q^T : A-fragments read directly from global (L1/L2-hot)
#pragma unroll
        for (int mt = 0; mt < 4; ++mt) {
            const u16* kr = kbase + (size_t)(kk + mt * 16 + l16) * HD + quad * 8;
            bf16x8 af0 = *(const bf16x8*)kr;
            bf16x8 af1 = *(const bf16x8*)(kr + 32);
            f32x4 z = (f32x4){0.f, 0.f, 0.f, 0.f};
            z = __builtin_amdgcn_mfma_f32_16x16x32_bf16(af0, qf0, z, 0, 0, 0);
            f32x4 s = __builtin_amdgcn_mfma_f32_16x16x32_bf16(af1, qf1, s = z, 0, 0, 0);

            f32x4 mv = *(const f32x4*)(mrow + kk + mt * 16);

            u32 er[4];
#pragma unroll
            for (int rg = 0; rg < 4; ++rg) {
                float e = __expf(s[rg] * mv[rg]);
                u32 u = __float_as_uint(e) + 0x8000u;
                er[rg] = u;
                l_part += __uint_as_float(u & 0xFFFF0000u);  // consistent with stored P
            }
            uint2 pk;
            pk.x = __builtin_amdgcn_perm(er[1], er[0], 0x07060302u);
            pk.y = __builtin_amdgcn_perm(er[3], er[2], 0x07060302u);
            *(uint2*)&Ps[qs * 72 + mt * 16 + quad * 4] = pk;   // wave-private strip
        }
        // no barrier: in-wave DS ordering + compiler lgkmcnt (pattern proven R0-R8)

        // PV: O = P * V ; V^T fragments read directly from global
        bf16x8 pf0 = *(const bf16x8*)&Ps[qs * 72 + quad * 8];
        bf16x8 pf1 = *(const bf16x8*)&Ps[qs * 72 + 32 + quad * 8];
#pragma unroll
        for (int nt = 0; nt < 4; ++nt) {
            const u16* vr = vtbase + (size_t)(nt * 16 + l16) * S_LEN + kk + quad * 8;
            bf16x8 vf0 = *(const bf16x8*)vr;
            bf16x8 vf1 = *(const bf16x8*)(vr + 32);
            o_acc[nt] = __builtin_amdgcn_mfma_f32_16x16x32_bf16(pf0, vf0, o_acc[nt], 0, 0, 0);
            o_acc[nt] = __builtin_amdgcn_mfma_f32_16x16x32_bf16(pf1, vf1, o_acc[nt], 0, 0, 0);
        }
    }

    // l reduction across quads (lanes sharing l16 end with identical sums)
    l_part += __shfl_xor(l_part, 16);
    l_part += __shfl_xor(l_part, 32);
    l_lds[w * 16 + l16] = l_part;        // wave-private; same-wave read below

#pragma unroll
    for (int reg = 0; reg < 4; ++reg) {
        int qloc = quad * 4 + reg;
        float inv = 1.0f / l_lds[w * 16 + qloc];
        u16* dst = aout + ((size_t)(b * S_LEN + s0 + qloc)) * HID + (g * R_REP + w) * HD;
#pragma unroll
        for (int nt = 0; nt < 4; ++nt)
            dst[nt * 16 + l16] = f2bf(o_acc[nt][reg] * inv);
    }
}

// ------- Output GEMM: BM=64 BN=128 BK=32, 512 blocks (2/CU); R1/R8-exact -------
__global__ __launch_bounds__(256) void gemm_o(const u16* __restrict__ A,
                                              const u16* __restrict__ WT,
                                              const float* __restrict__ bo,
                                              const float* __restrict__ Xres,
                                              float* __restrict__ out) {
    __shared__ __align__(16) u16 As[2][64 * 32];
    __shared__ __align__(16) u16 Bs[2][128 * 32];
    int tid = threadIdx.x;
    int w = tid >> 6, lane = tid & 63, quad = lane >> 4, l16 = lane & 15;
    int m0 = blockIdx.y * 64, n0 = blockIdx.x * 128;
    int wr = (w >> 1) * 32, wc = (w & 1) * 64;
    int srow = lane >> 2, scol = (lane & 3) * 8;

    const u16* aP  = &A[(size_t)(m0 + w * 16 + srow) * 2048 + scol];
    const u16* bP0 = &WT[(size_t)(n0 + w * 32 + srow) * 2048 + scol];
    const u16* bP1 = &WT[(size_t)(n0 + w * 32 + 16 + srow) * 2048 + scol];

    f32x4 acc[2][4];
#pragma unroll
    for (int i = 0; i < 2; ++i)
#pragma unroll
        for (int j = 0; j < 4; ++j) acc[i][j] = (f32x4){0.f, 0.f, 0.f, 0.f};

    gload_lds16(aP,  &As[0][(w * 16) * 32]);
    gload_lds16(bP0, &Bs[0][(w * 32) * 32]);
    gload_lds16(bP1, &Bs[0][(w * 32 + 16) * 32]);
    __syncthreads();

    int cur = 0;
    for (int k0 = 0; k0 < 2048; k0 += 32) {
        int kn = k0 + 32;
        if (kn < 2048) {
            gload_lds16(aP + kn,  &As[cur ^ 1][(w * 16) * 32]);
            gload_lds16(bP0 + kn, &Bs[cur ^ 1][(w * 32) * 32]);
            gload_lds16(bP1 + kn, &Bs[cur ^ 1][(w * 32 + 16) * 32]);
        }
        bf16x8 af[2], bfr[4];
#pragma unroll
        for (int mt = 0; mt < 2; ++mt)
            af[mt] = *(const bf16x8*)&As[cur][(wr + mt * 16 + l16) * 32 + quad * 8];
#pragma unroll
        for (int nt = 0; nt < 4; ++nt)
            bfr[nt] = *(const bf16x8*)&Bs[cur][(wc + nt * 16 + l16) * 32 + quad * 8];
#pragma unroll
        for (int mt = 0; mt < 2; ++mt)
#pragma unroll
            for (int nt = 0; nt < 4; ++nt)
                acc[mt][nt] = __builtin_amdgcn_mfma_f32_16x16x32_bf16(af[mt], bfr[nt], acc[mt][nt], 0, 0, 0);
        __syncthreads();
        cur ^= 1;
    }

#pragma unroll
    for (int nt = 0; nt < 4; ++nt) {
        int n = n0 + wc + nt * 16 + l16;
        float bias = bo[n];
#pragma unroll
        for (int mt = 0; mt < 2; ++mt) {
#pragma unroll
            for (int reg = 0; reg < 4; ++reg) {
                int m = m0 + wr + mt * 16 + quad * 4 + reg;
                out[(size_t)m * 2048 + n] = acc[mt][nt][reg] + bias + Xres[(size_t)m * 2048 + n];
            }
        }
    }
}

extern "C" void kernel_launch(void* const* d_in, const int* in_sizes, int n_in,
                              void* d_out, int out_size, void* d_ws, size_t ws_size,
                              hipStream_t stream) {
    const float* x    = (const float*)d_in[0];
    const float* mask = (const float*)d_in[1];
    const float* Wq   = (const float*)d_in[2];
    const float* bq   = (const float*)d_in[3];
    const float* Wk   = (const float*)d_in[4];
    const float* bk   = (const float*)d_in[5];
    const float* Wv   = (const float*)d_in[6];
    const float* bv   = (const float*)d_in[7];
    const float* Wo   = (const float*)d_in[8];
    const float* bo   = (const float*)d_in[9];
    float* out = (float*)d_out;

    u16* ws = (u16*)d_ws;
    size_t off = 0;
    u16* WqkvT = ws + off; off += (size_t)NQKV * 2048;
    u16* WoT   = ws + off; off += (size_t)2048 * 2048;
    u16* q_buf = ws + off; off += (size_t)BATCH * G_KV * R_REP * S_LEN * HD;
    u16* k_buf = ws + off; off += (size_t)BATCH * G_KV * S_LEN * HD;
    u16* v_buf = ws + off; off += (size_t)BATCH * G_KV * S_LEN * HD;  // V^T [b][g][d][s]
    u16* a_out = ws + off; off += (size_t)2048 * 2048;
    u16* Xb    = a_out;   // alias: consumed by gemm_qkv before attn writes a_out

    prep<<<dim3(12288), 256, 0, stream>>>(x, Wq, Wk, Wv, Wo, Xb, WqkvT, WoT);

    gemm_qkv<<<dim3(NQKV / 128, 2048 / 64), 256, 0, stream>>>(Xb, WqkvT, bq, bk, bv,
                                                              q_buf, k_buf, v_buf);

    attn_mfma<<<dim3(BATCH * G_KV * 64), 256, 0, stream>>>(
        q_buf, k_buf, v_buf, mask, a_out);

    gemm_o<<<dim3(2048 / 128, 2048 / 64), 256, 0, stream>>>(a_out, WoT, bo, x, out);
}

// Round 11
// 232.604 us; speedup vs baseline: 1.4800x; 1.4800x over previous
//
#include <hip/hip_runtime.h>

typedef unsigned short u16;
typedef unsigned int u32;
typedef __attribute__((ext_vector_type(8))) short bf16x8;
typedef __attribute__((ext_vector_type(4))) float f32x4;

#define HID 2048
#define S_LEN 1024
#define BATCH 2
#define G_KV 8
#define R_REP 4
#define HD 64
#define NQKV 3072  // 2048 q + 512 k + 512 v

__device__ __forceinline__ u16 f2bf(float f) {
    union { u32 u; float ff; } x; x.ff = f;
    u32 u = x.u;
    u += 0x7FFFu + ((u >> 16) & 1u);
    return (u16)(u >> 16);
}

__device__ __forceinline__ void gload_lds16(const void* g, void* l) {
    __builtin_amdgcn_global_load_lds((const __attribute__((address_space(1))) void*)g,
                                     (__attribute__((address_space(3))) void*)l,
                                     16, 0, 0);
}

// ------- Fused prep: cvt_x | transpose_qkv | transpose_cvt(Wo) (R8-proven) -------
__global__ __launch_bounds__(256) void prep(const float* __restrict__ x,
                                            const float* __restrict__ Wq,
                                            const float* __restrict__ Wk,
                                            const float* __restrict__ Wv,
                                            const float* __restrict__ Wo,
                                            u16* __restrict__ Xb,
                                            u16* __restrict__ WqkvT,
                                            u16* __restrict__ WoT) {
    __shared__ float tile[32][33];
    int bid = blockIdx.x, tid = threadIdx.x;

    if (bid < 2048) {
        int i = (bid * 256 + tid) * 8;
        float4 a = *(const float4*)(x + i);
        float4 b = *(const float4*)(x + i + 4);
        u16 t[8] = {f2bf(a.x), f2bf(a.y), f2bf(a.z), f2bf(a.w),
                    f2bf(b.x), f2bf(b.y), f2bf(b.z), f2bf(b.w)};
        *(uint4*)(Xb + i) = *(const uint4*)t;
        return;
    }

    int tx = tid & 31, ty = tid >> 5;
    if (bid < 8192) {
        int local = bid - 2048;
        int n0 = (local % 96) * 32, k0 = (local / 96) * 32;
        const float* in; int N, nc0;
        if (n0 < 2048)      { in = Wq; N = 2048; nc0 = n0; }
        else if (n0 < 2560) { in = Wk; N = 512;  nc0 = n0 - 2048; }
        else                { in = Wv; N = 512;  nc0 = n0 - 2560; }
#pragma unroll
        for (int j = 0; j < 4; ++j)
            tile[ty + j * 8][tx] = in[(size_t)(k0 + ty + j * 8) * N + nc0 + tx];
        __syncthreads();
#pragma unroll
        for (int j = 0; j < 4; ++j)
            WqkvT[(size_t)(n0 + ty + j * 8) * 2048 + k0 + tx] = f2bf(tile[tx][ty + j * 8]);
        return;
    }

    {
        int local = bid - 8192;
        int n0 = (local & 63) * 32, k0 = (local >> 6) * 32;
#pragma unroll
        for (int j = 0; j < 4; ++j)
            tile[ty + j * 8][tx] = Wo[(size_t)(k0 + ty + j * 8) * 2048 + n0 + tx];
        __syncthreads();
#pragma unroll
        for (int j = 0; j < 4; ++j)
            WoT[(size_t)(n0 + ty + j * 8) * 2048 + k0 + tx] = f2bf(tile[tx][ty + j * 8]);
    }
}

// ------- QKV GEMM: BM=64 BN=128 BK=32, 768 blocks (3/CU); R1/R8-exact (best) -------
__global__ __launch_bounds__(256) void gemm_qkv(const u16* __restrict__ Xb,
                                                const u16* __restrict__ WT,
                                                const float* __restrict__ bq,
                                                const float* __restrict__ bk,
                                                const float* __restrict__ bv,
                                                u16* __restrict__ qb,
                                                u16* __restrict__ kb,
                                                u16* __restrict__ vb) {
    __shared__ __align__(16) u16 As[2][64 * 32];
    __shared__ __align__(16) u16 Bs[2][128 * 32];
    int tid = threadIdx.x;
    int w = tid >> 6, lane = tid & 63, quad = lane >> 4, l16 = lane & 15;
    int m0 = blockIdx.y * 64, n0 = blockIdx.x * 128;
    int wr = (w >> 1) * 32, wc = (w & 1) * 64;   // wave tile 32x64
    int srow = lane >> 2, scol = (lane & 3) * 8;

    const u16* aP  = &Xb[(size_t)(m0 + w * 16 + srow) * 2048 + scol];
    const u16* bP0 = &WT[(size_t)(n0 + w * 32 + srow) * 2048 + scol];
    const u16* bP1 = &WT[(size_t)(n0 + w * 32 + 16 + srow) * 2048 + scol];

    f32x4 acc[2][4];
#pragma unroll
    for (int i = 0; i < 2; ++i)
#pragma unroll
        for (int j = 0; j < 4; ++j) acc[i][j] = (f32x4){0.f, 0.f, 0.f, 0.f};

    gload_lds16(aP,  &As[0][(w * 16) * 32]);
    gload_lds16(bP0, &Bs[0][(w * 32) * 32]);
    gload_lds16(bP1, &Bs[0][(w * 32 + 16) * 32]);
    __syncthreads();

    int cur = 0;
    for (int k0 = 0; k0 < 2048; k0 += 32) {
        int kn = k0 + 32;
        if (kn < 2048) {
            gload_lds16(aP + kn,  &As[cur ^ 1][(w * 16) * 32]);
            gload_lds16(bP0 + kn, &Bs[cur ^ 1][(w * 32) * 32]);
            gload_lds16(bP1 + kn, &Bs[cur ^ 1][(w * 32 + 16) * 32]);
        }
        bf16x8 af[2], bfr[4];
#pragma unroll
        for (int mt = 0; mt < 2; ++mt)
            af[mt] = *(const bf16x8*)&As[cur][(wr + mt * 16 + l16) * 32 + quad * 8];
#pragma unroll
        for (int nt = 0; nt < 4; ++nt)
            bfr[nt] = *(const bf16x8*)&Bs[cur][(wc + nt * 16 + l16) * 32 + quad * 8];
#pragma unroll
        for (int mt = 0; mt < 2; ++mt)
#pragma unroll
            for (int nt = 0; nt < 4; ++nt)
                acc[mt][nt] = __builtin_amdgcn_mfma_f32_16x16x32_bf16(af[mt], bfr[nt], acc[mt][nt], 0, 0, 0);
        __syncthreads();
        cur ^= 1;
    }

#pragma unroll
    for (int nt = 0; nt < 4; ++nt) {
        int n = n0 + wc + nt * 16 + l16;
        float bias;
        if (n < 2048) bias = bq[n];
        else if (n < 2560) bias = bk[n - 2048];
        else bias = bv[n - 2560];
#pragma unroll
        for (int mt = 0; mt < 2; ++mt) {
#pragma unroll
            for (int reg = 0; reg < 4; ++reg) {
                int m = m0 + wr + mt * 16 + quad * 4 + reg;
                float val = acc[mt][nt][reg] + bias;
                int b = m >> 10, s = m & 1023;
                if (n < 2048) {
                    int g = n >> 8, r = (n >> 6) & 3, d = n & 63;
                    qb[((((size_t)(b * G_KV + g) * R_REP + r) * S_LEN) + s) * HD + d] = f2bf(val * 0.125f);
                } else if (n < 2560) {
                    int n2 = n - 2048, g = n2 >> 6, d = n2 & 63;
                    kb[(((size_t)(b * G_KV + g) * S_LEN) + s) * HD + d] = f2bf(val);
                } else {
                    int n2 = n - 2560, g = n2 >> 6, d = n2 & 63;
                    vb[(((size_t)(b * G_KV + g) * HD + d) * S_LEN) + s] = f2bf(val);  // V^T
                }
            }
        }
    }
}

// ------- Attention v4: block = 4 heads x 32 q-rows of one (b,g); grid 512 (2/CU).
//         K/V staged once per kt serve BOTH q-halves: K/V fragment reads are reused
//         (af/vf independent of q), so LDS reads/MFMA drop 1.13 -> 0.75, staging
//         writes and K/V global traffic per output halve. Staging-as-pipeline kept
//         (v3 lesson: removing it exposes raw load latency). -------
__global__ __launch_bounds__(256) void attn_mfma(const u16* __restrict__ qbuf,
                                                 const u16* __restrict__ kbuf,
                                                 const u16* __restrict__ vtbuf,
                                                 const float* __restrict__ mask,
                                                 u16* __restrict__ aout) {
    __shared__ __align__(16) u16 Ks[64 * 72];    // [key][dim]
    __shared__ __align__(16) u16 Vs[64 * 72];    // [dim][key]
    __shared__ __align__(16) u16 Ps[2][64 * 72]; // [half][wave-strip q][key]
    __shared__ __align__(16) float Ms[32 * 68];  // [q-local][key] fp32
    __shared__ float l_lds[128];

    int d = blockIdx.x;                   // 512 = B*G*32
    int qblk = d & 31, g = (d >> 5) & 7, b = d >> 8;
    int s0 = qblk * 32;

    int tid = threadIdx.x;
    int w = tid >> 6, lane = tid & 63, quad = lane >> 4, l16 = lane & 15;
    int qs = w * 16 + l16;                // wave-private strip row

    // Q: head r = w; lo rows s0..s0+15 (col l16), hi rows s0+16..s0+31
    const u16* qrow = qbuf +
        ((((size_t)(b * G_KV + g) * R_REP + w) * S_LEN) + s0 + l16) * HD;
    bf16x8 qf0_lo = *(const bf16x8*)(qrow + quad * 8);
    bf16x8 qf1_lo = *(const bf16x8*)(qrow + 32 + quad * 8);
    bf16x8 qf0_hi = *(const bf16x8*)(qrow + 16 * HD + quad * 8);
    bf16x8 qf1_hi = *(const bf16x8*)(qrow + 16 * HD + 32 + quad * 8);

    f32x4 o_lo[4], o_hi[4];
#pragma unroll
    for (int i = 0; i < 4; ++i) {
        o_lo[i] = (f32x4){0.f, 0.f, 0.f, 0.f};
        o_hi[i] = (f32x4){0.f, 0.f, 0.f, 0.f};
    }
    float l_lo = 0.f, l_hi = 0.f;

    const u16* kbase  = kbuf  + (size_t)(b * G_KV + g) * S_LEN * HD;
    const u16* vtbase = vtbuf + (size_t)(b * G_KV + g) * HD * S_LEN;
    // mask staging: thread t covers row t>>3 (0..31), cols (t&7)*8 .. +8
    int msrow = tid >> 3, mscol = (tid & 7) * 8;
    const float* mstage = mask + ((size_t)b * S_LEN + s0 + msrow) * S_LEN + mscol;

    int srow = tid >> 2, sc = (tid & 3) * 16;

    // prologue: prefetch tile 0 into registers
    uint4 kp0, kp1, vp0, vp1;
    f32x4 mp0, mp1;
    {
        const u16* kr = kbase + (size_t)srow * HD + sc;
        kp0 = *(const uint4*)kr; kp1 = *(const uint4*)(kr + 8);
        const u16* vr = vtbase + (size_t)srow * S_LEN + sc;
        vp0 = *(const uint4*)vr; vp1 = *(const uint4*)(vr + 8);
        mp0 = *(const f32x4*)mstage; mp1 = *(const f32x4*)(mstage + 4);
    }

    for (int kt = 0; kt < 16; ++kt) {
        __syncthreads();    // prior iteration's LDS reads complete
        *(uint4*)&Ks[srow * 72 + sc]     = kp0;
        *(uint4*)&Ks[srow * 72 + sc + 8] = kp1;
        *(uint4*)&Vs[srow * 72 + sc]     = vp0;
        *(uint4*)&Vs[srow * 72 + sc + 8] = vp1;
        *(f32x4*)&Ms[msrow * 68 + mscol]     = mp0;
        *(f32x4*)&Ms[msrow * 68 + mscol + 4] = mp1;
        __syncthreads();    // staging visible

        // prefetch kt+1 (overlaps compute)
        if (kt < 15) {
            int nk = (kt + 1) * 64;
            const u16* kr = kbase + (size_t)(nk + srow) * HD + sc;
            kp0 = *(const uint4*)kr; kp1 = *(const uint4*)(kr + 8);
            const u16* vr = vtbase + (size_t)srow * S_LEN + nk + sc;
            vp0 = *(const uint4*)vr; vp1 = *(const uint4*)(vr + 8);
            mp0 = *(const f32x4*)(mstage + nk);
            mp1 = *(const f32x4*)(mstage + nk + 4);
        }

        // S^T = K * Q^T for both q-halves; af shared
#pragma unroll
        for (int mt = 0; mt < 4; ++mt) {
            bf16x8 af0 = *(const bf16x8*)&Ks[(mt * 16 + l16) * 72 + quad * 8];
            bf16x8 af1 = *(const bf16x8*)&Ks[(mt * 16 + l16) * 72 + 32 + quad * 8];
            f32x4 z0 = (f32x4){0.f, 0.f, 0.f, 0.f};
            z0 = __builtin_amdgcn_mfma_f32_16x16x32_bf16(af0, qf0_lo, z0, 0, 0, 0);
            f32x4 s_lo = __builtin_amdgcn_mfma_f32_16x16x32_bf16(af1, qf1_lo, z0, 0, 0, 0);
            f32x4 z1 = (f32x4){0.f, 0.f, 0.f, 0.f};
            z1 = __builtin_amdgcn_mfma_f32_16x16x32_bf16(af0, qf0_hi, z1, 0, 0, 0);
            f32x4 s_hi = __builtin_amdgcn_mfma_f32_16x16x32_bf16(af1, qf1_hi, z1, 0, 0, 0);

            f32x4 mv_lo = *(const f32x4*)&Ms[l16 * 68 + mt * 16 + quad * 4];
            f32x4 mv_hi = *(const f32x4*)&Ms[(16 + l16) * 68 + mt * 16 + quad * 4];

            u32 er[4];
#pragma unroll
            for (int rg = 0; rg < 4; ++rg) {
                float e = __expf(s_lo[rg] * mv_lo[rg]);
                u32 u = __float_as_uint(e) + 0x8000u;
                er[rg] = u;
                l_lo += __uint_as_float(u & 0xFFFF0000u);
            }
            uint2 pk;
            pk.x = __builtin_amdgcn_perm(er[1], er[0], 0x07060302u);
            pk.y = __builtin_amdgcn_perm(er[3], er[2], 0x07060302u);
            *(uint2*)&Ps[0][qs * 72 + mt * 16 + quad * 4] = pk;

#pragma unroll
            for (int rg = 0; rg < 4; ++rg) {
                float e = __expf(s_hi[rg] * mv_hi[rg]);
                u32 u = __float_as_uint(e) + 0x8000u;
                er[rg] = u;
                l_hi += __uint_as_float(u & 0xFFFF0000u);
            }
            pk.x = __builtin_amdgcn_perm(er[1], er[0], 0x07060302u);
            pk.y = __builtin_amdgcn_perm(er[3], er[2], 0x07060302u);
            *(uint2*)&Ps[1][qs * 72 + mt * 16 + quad * 4] = pk;
        }
        // no barrier: P strips are wave-private (in-wave DS ordering, proven R0-R8)

        // PV for both halves; vf shared
        bf16x8 pf0_lo = *(const bf16x8*)&Ps[0][qs * 72 + quad * 8];
        bf16x8 pf1_lo = *(const bf16x8*)&Ps[0][qs * 72 + 32 + quad * 8];
        bf16x8 pf0_hi = *(const bf16x8*)&Ps[1][qs * 72 + quad * 8];
        bf16x8 pf1_hi = *(const bf16x8*)&Ps[1][qs * 72 + 32 + quad * 8];
#pragma unroll
        for (int nt = 0; nt < 4; ++nt) {
            bf16x8 vf0 = *(const bf16x8*)&Vs[(nt * 16 + l16) * 72 + quad * 8];
            bf16x8 vf1 = *(const bf16x8*)&Vs[(nt * 16 + l16) * 72 + 32 + quad * 8];
            o_lo[nt] = __builtin_amdgcn_mfma_f32_16x16x32_bf16(pf0_lo, vf0, o_lo[nt], 0, 0, 0);
            o_lo[nt] = __builtin_amdgcn_mfma_f32_16x16x32_bf16(pf1_lo, vf1, o_lo[nt], 0, 0, 0);
            o_hi[nt] = __builtin_amdgcn_mfma_f32_16x16x32_bf16(pf0_hi, vf0, o_hi[nt], 0, 0, 0);
            o_hi[nt] = __builtin_amdgcn_mfma_f32_16x16x32_bf16(pf1_hi, vf1, o_hi[nt], 0, 0, 0);
        }
    }

    // l reductions across quads (lanes sharing l16), wave-private strips
    l_lo += __shfl_xor(l_lo, 16);
    l_lo += __shfl_xor(l_lo, 32);
    l_hi += __shfl_xor(l_hi, 16);
    l_hi += __shfl_xor(l_hi, 32);
    l_lds[qs] = l_lo;
    l_lds[64 + qs] = l_hi;

#pragma unroll
    for (int reg = 0; reg < 4; ++reg) {
        int qloc = quad * 4 + reg;
        float inv_lo = 1.0f / l_lds[w * 16 + qloc];
        float inv_hi = 1.0f / l_lds[64 + w * 16 + qloc];
        u16* dst_lo = aout + ((size_t)(b * S_LEN + s0 + qloc)) * HID + (g * R_REP + w) * HD;
        u16* dst_hi = dst_lo + (size_t)16 * HID;
#pragma unroll
        for (int nt = 0; nt < 4; ++nt) {
            dst_lo[nt * 16 + l16] = f2bf(o_lo[nt][reg] * inv_lo);
            dst_hi[nt * 16 + l16] = f2bf(o_hi[nt][reg] * inv_hi);
        }
    }
}

// ------- Output GEMM: BM=64 BN=128 BK=32, 512 blocks (2/CU); R1/R8-exact -------
__global__ __launch_bounds__(256) void gemm_o(const u16* __restrict__ A,
                                              const u16* __restrict__ WT,
                                              const float* __restrict__ bo,
                                              const float* __restrict__ Xres,
                                              float* __restrict__ out) {
    __shared__ __align__(16) u16 As[2][64 * 32];
    __shared__ __align__(16) u16 Bs[2][128 * 32];
    int tid = threadIdx.x;
    int w = tid >> 6, lane = tid & 63, quad = lane >> 4, l16 = lane & 15;
    int m0 = blockIdx.y * 64, n0 = blockIdx.x * 128;
    int wr = (w >> 1) * 32, wc = (w & 1) * 64;
    int srow = lane >> 2, scol = (lane & 3) * 8;

    const u16* aP  = &A[(size_t)(m0 + w * 16 + srow) * 2048 + scol];
    const u16* bP0 = &WT[(size_t)(n0 + w * 32 + srow) * 2048 + scol];
    const u16* bP1 = &WT[(size_t)(n0 + w * 32 + 16 + srow) * 2048 + scol];

    f32x4 acc[2][4];
#pragma unroll
    for (int i = 0; i < 2; ++i)
#pragma unroll
        for (int j = 0; j < 4; ++j) acc[i][j] = (f32x4){0.f, 0.f, 0.f, 0.f};

    gload_lds16(aP,  &As[0][(w * 16) * 32]);
    gload_lds16(bP0, &Bs[0][(w * 32) * 32]);
    gload_lds16(bP1, &Bs[0][(w * 32 + 16) * 32]);
    __syncthreads();

    int cur = 0;
    for (int k0 = 0; k0 < 2048; k0 += 32) {
        int kn = k0 + 32;
        if (kn < 2048) {
            gload_lds16(aP + kn,  &As[cur ^ 1][(w * 16) * 32]);
            gload_lds16(bP0 + kn, &Bs[cur ^ 1][(w * 32) * 32]);
            gload_lds16(bP1 + kn, &Bs[cur ^ 1][(w * 32 + 16) * 32]);
        }
        bf16x8 af[2], bfr[4];
#pragma unroll
        for (int mt = 0; mt < 2; ++mt)
            af[mt] = *(const bf16x8*)&As[cur][(wr + mt * 16 + l16) * 32 + quad * 8];
#pragma unroll
        for (int nt = 0; nt < 4; ++nt)
            bfr[nt] = *(const bf16x8*)&Bs[cur][(wc + nt * 16 + l16) * 32 + quad * 8];
#pragma unroll
        for (int mt = 0; mt < 2; ++mt)
#pragma unroll
            for (int nt = 0; nt < 4; ++nt)
                acc[mt][nt] = __builtin_amdgcn_mfma_f32_16x16x32_bf16(af[mt], bfr[nt], acc[mt][nt], 0, 0, 0);
        __syncthreads();
        cur ^= 1;
    }

#pragma unroll
    for (int nt = 0; nt < 4; ++nt) {
        int n = n0 + wc + nt * 16 + l16;
        float bias = bo[n];
#pragma unroll
        for (int mt = 0; mt < 2; ++mt) {
#pragma unroll
            for (int reg = 0; reg < 4; ++reg) {
                int m = m0 + wr + mt * 16 + quad * 4 + reg;
                out[(size_t)m * 2048 + n] = acc[mt][nt][reg] + bias + Xres[(size_t)m * 2048 + n];
            }
        }
    }
}

extern "C" void kernel_launch(void* const* d_in, const int* in_sizes, int n_in,
                              void* d_out, int out_size, void* d_ws, size_t ws_size,
                              hipStream_t stream) {
    const float* x    = (const float*)d_in[0];
    const float* mask = (const float*)d_in[1];
    const float* Wq   = (const float*)d_in[2];
    const float* bq   = (const float*)d_in[3];
    const float* Wk   = (const float*)d_in[4];
    const float* bk   = (const float*)d_in[5];
    const float* Wv   = (const float*)d_in[6];
    const float* bv   = (const float*)d_in[7];
    const float* Wo   = (const float*)d_in[8];
    const float* bo   = (const float*)d_in[9];
    float* out = (float*)d_out;

    u16* ws = (u16*)d_ws;
    size_t off = 0;
    u16* WqkvT = ws + off; off += (size_t)NQKV * 2048;
    u16* WoT   = ws + off; off += (size_t)2048 * 2048;
    u16* q_buf = ws + off; off += (size_t)BATCH * G_KV * R_REP * S_LEN * HD;
    u16* k_buf = ws + off; off += (size_t)BATCH * G_KV * S_LEN * HD;
    u16* v_buf = ws + off; off += (size_t)BATCH * G_KV * S_LEN * HD;  // V^T [b][g][d][s]
    u16* a_out = ws + off; off += (size_t)2048 * 2048;
    u16* Xb    = a_out;   // alias: consumed by gemm_qkv before attn writes a_out

    prep<<<dim3(12288), 256, 0, stream>>>(x, Wq, Wk, Wv, Wo, Xb, WqkvT, WoT);

    gemm_qkv<<<dim3(NQKV / 128, 2048 / 64), 256, 0, stream>>>(Xb, WqkvT, bq, bk, bv,
                                                              q_buf, k_buf, v_buf);

    attn_mfma<<<dim3(BATCH * G_KV * 32), 256, 0, stream>>>(
        q_buf, k_buf, v_buf, mask, a_out);

    gemm_o<<<dim3(2048 / 128, 2048 / 64), 256, 0, stream>>>(a_out, WoT, bo, x, out);
}